// Round 1
// baseline (477.028 us; speedup 1.0000x reference)
//
#include <hip/hip_runtime.h>
#include <hip/hip_bf16.h>

#define NT 8192   // total nodes (2 graphs)
#define NN 4096   // nodes per graph
#define CD 128    // channels
#define NE 65536  // edges per graph

typedef __attribute__((ext_vector_type(8))) short bf16x8;
typedef __attribute__((ext_vector_type(16))) float f32x16;

// ---------------- weight transposes (once) ----------------
__global__ void k_transW(const float* __restrict__ W1, const float* __restrict__ W2,
                         const float* __restrict__ WL,
                         float* __restrict__ WT1, float* __restrict__ WT2,
                         float* __restrict__ WTL) {
  int idx = blockIdx.x * 256 + threadIdx.x;
  if (idx < 32768) { int c = idx >> 8, k = idx & 255; WT1[k * 128 + c] = W1[idx]; }
  else if (idx < 65536) { int j = idx - 32768; int c = j >> 8, k = j & 255; WT2[k * 128 + c] = W2[j]; }
  else if (idx < 81920) { int j = idx - 65536; int c = j >> 7, k = j & 127; WTL[k * 128 + c] = WL[j]; }
}

// ---------------- CSR build (once; edges shared by both layers) ----------------
__global__ void k_deg(const int* __restrict__ EI1, const int* __restrict__ EI2,
                      int* __restrict__ DEG) {
  int idx = blockIdx.x * 256 + threadIdx.x;   // 131072
  int g = idx >> 16, e = idx & 65535;
  const int* src = g ? EI2 : EI1;
  atomicAdd(&DEG[g * NN + src[e]], 1);
}

__global__ void k_scanoff(const int* __restrict__ DEG, int* __restrict__ OFFS,
                          int* __restrict__ CURS) {
  int g = blockIdx.x, tid = threadIdx.x;
  __shared__ int part[256];
  int loc[16];
  int s = 0;
  #pragma unroll
  for (int i = 0; i < 16; ++i) { loc[i] = s; s += DEG[g * NN + tid * 16 + i]; }
  part[tid] = s;
  __syncthreads();
  for (int d = 1; d < 256; d <<= 1) {
    int v = part[tid];
    int o = (tid >= d) ? part[tid - d] : 0;
    __syncthreads();
    part[tid] = v + o;
    __syncthreads();
  }
  int excl = tid ? part[tid - 1] : 0;
  #pragma unroll
  for (int i = 0; i < 16; ++i) {
    int o = excl + loc[i];
    OFFS[g * (NN + 1) + tid * 16 + i] = o;
    CURS[g * NN + tid * 16 + i] = o;
  }
  if (tid == 255) OFFS[g * (NN + 1) + NN] = part[255];
}

__global__ void k_fill(const int* __restrict__ EI1, const int* __restrict__ EI2,
                       int* __restrict__ CURS, int* __restrict__ ADJ) {
  int idx = blockIdx.x * 256 + threadIdx.x;
  int g = idx >> 16, e = idx & 65535;
  const int* ei = g ? EI2 : EI1;
  int s = ei[e], d = ei[NE + e];
  int pos = atomicAdd(&CURS[g * NN + s], 1);
  ADJ[g * NE + pos] = d;
}

// ---------------- per-layer attention scalars ----------------
// vl = wl^T al, vr = wr^T ar, cl = bl.al, cr = br.ar   (HEAD=1 collapse)
__global__ void k_params(const float* __restrict__ wlw, const float* __restrict__ wlb,
                         const float* __restrict__ wrw, const float* __restrict__ wrb,
                         const float* __restrict__ alv, const float* __restrict__ arv,
                         float* __restrict__ VP) {
  int c = threadIdx.x;  // 128
  float sl = 0.f, sr = 0.f;
  for (int h = 0; h < 128; ++h) {
    sl += wlw[h * 128 + c] * alv[h];
    sr += wrw[h * 128 + c] * arv[h];
  }
  VP[c] = sl;
  VP[128 + c] = sr;
  if (c < 2) {
    const float* b = c ? wrb : wlb;
    const float* a = c ? arv : alv;
    float s = 0.f;
    for (int h = 0; h < 128; ++h) s += b[h] * a[h];
    VP[256 + c] = s;
  }
}

// a_l[i] = X[i].vl + cl ; a_r[i] = X[i].vr + cr    (one wave per row)
__global__ void k_alar(const float* __restrict__ X, const float* __restrict__ VP,
                       float* __restrict__ AL, float* __restrict__ AR) {
  int lane = threadIdx.x & 63;
  int row = blockIdx.x * 4 + (threadIdx.x >> 6);
  float x0 = X[row * 128 + lane], x1 = X[row * 128 + 64 + lane];
  float sl = x0 * VP[lane] + x1 * VP[64 + lane];
  float sr = x0 * VP[128 + lane] + x1 * VP[192 + lane];
  #pragma unroll
  for (int m = 1; m < 64; m <<= 1) {
    sl += __shfl_xor(sl, m, 64);
    sr += __shfl_xor(sr, m, 64);
  }
  if (lane == 0) { AL[row] = sl + VP[256]; AR[row] = sr + VP[257]; }
}

// rank of each j under total order (a_r, j)  -> O(N^2) chunked count, int atomics
__global__ void k_rank(const float* __restrict__ AR, int* __restrict__ RANK) {
  __shared__ float tile[1024];
  int j = blockIdx.x * 256 + threadIdx.x;
  int base = blockIdx.y * 1024;
  for (int t = threadIdx.x; t < 1024; t += 256) tile[t] = AR[base + t];
  __syncthreads();
  float aj = AR[j];
  int cnt = 0;
  #pragma unroll 8
  for (int u = 0; u < 1024; ++u) {
    float a2 = tile[u];
    cnt += (a2 < aj || (a2 == aj && (base + u) < j)) ? 1 : 0;
  }
  atomicAdd(&RANK[j], cnt);
}

// scatter permutation + sorted tables: arS, w1S=exp(ar), w2S=exp(0.2 ar)
__global__ void k_perm(const int* __restrict__ RANK, const float* __restrict__ AR,
                       int* __restrict__ PERM, float* __restrict__ ARS,
                       float* __restrict__ W1S, float* __restrict__ W2S) {
  int j = blockIdx.x * 256 + threadIdx.x;
  int r = RANK[j];
  float a = AR[j];
  PERM[r] = j;
  ARS[r] = a;
  W1S[r] = __expf(a);
  W2S[r] = __expf(0.2f * a);
}

// hierarchical prefix sums along sorted axis: chunks of 64, 128 chunks
__global__ __launch_bounds__(320) void k_scanA(
    const float* __restrict__ X, const int* __restrict__ PERM,
    const float* __restrict__ W1S, const float* __restrict__ W2S,
    float* __restrict__ P1, float* __restrict__ P2,
    float* __restrict__ CT1, float* __restrict__ CT2,
    float* __restrict__ Q1L, float* __restrict__ Q2L,
    float* __restrict__ QCT1, float* __restrict__ QCT2) {
  __shared__ int pc[64];
  __shared__ float w1[64], w2[64];
  int chunk = blockIdx.x, tid = threadIdx.x;
  if (tid < 64) {
    int r = chunk * 64 + tid;
    pc[tid] = PERM[r];
    w1[tid] = W1S[r];
    w2[tid] = W2S[r];
  }
  __syncthreads();
  if (tid < 128) {
    int c = tid;
    float acc = 0.f;
    #pragma unroll 4
    for (int t = 0; t < 64; ++t) {
      acc += w1[t] * X[pc[t] * 128 + c];
      P1[(chunk * 64 + t) * 128 + c] = acc;
    }
    CT1[chunk * 128 + c] = acc;
  } else if (tid < 256) {
    int c = tid - 128;
    float acc = 0.f;
    #pragma unroll 4
    for (int t = 0; t < 64; ++t) {
      acc += w2[t] * X[pc[t] * 128 + c];
      P2[(chunk * 64 + t) * 128 + c] = acc;
    }
    CT2[chunk * 128 + c] = acc;
  } else if (tid == 256) {
    float acc = 0.f;
    for (int t = 0; t < 64; ++t) { acc += w1[t]; Q1L[chunk * 64 + t] = acc; }
    QCT1[chunk] = acc;
  } else if (tid == 257) {
    float acc = 0.f;
    for (int t = 0; t < 64; ++t) { acc += w2[t]; Q2L[chunk * 64 + t] = acc; }
    QCT2[chunk] = acc;
  }
}

__global__ __launch_bounds__(320) void k_scanB(
    const float* __restrict__ CT1, const float* __restrict__ CT2,
    const float* __restrict__ QCT1, const float* __restrict__ QCT2,
    float* __restrict__ OFF1, float* __restrict__ OFF2,
    float* __restrict__ QOF1, float* __restrict__ QOF2) {
  int tid = threadIdx.x;
  if (tid < 128) {
    float acc = 0.f;
    #pragma unroll 8
    for (int ch = 0; ch < 128; ++ch) { acc += CT1[ch * 128 + tid]; OFF1[ch * 128 + tid] = acc; }
  } else if (tid < 256) {
    int c = tid - 128;
    float acc = 0.f;
    #pragma unroll 8
    for (int ch = 0; ch < 128; ++ch) { acc += CT2[ch * 128 + c]; OFF2[ch * 128 + c] = acc; }
  } else if (tid == 256) {
    float acc = 0.f;
    for (int ch = 0; ch < 128; ++ch) { acc += QCT1[ch]; QOF1[ch] = acc; }
  } else if (tid == 257) {
    float acc = 0.f;
    for (int ch = 0; ch < 128; ++ch) { acc += QCT2[ch]; QOF2[ch] = acc; }
  }
}

// ot[i] = x[i] - (A1*suffix1 + A2*prefix2)/(A1*qsuf1 + A2*qpre2)
__global__ void k_combine(const float* __restrict__ X, const float* __restrict__ AL,
                          const float* __restrict__ ARS,
                          const float* __restrict__ P1, const float* __restrict__ P2,
                          const float* __restrict__ OFF1, const float* __restrict__ OFF2,
                          const float* __restrict__ Q1L, const float* __restrict__ Q2L,
                          const float* __restrict__ QOF1, const float* __restrict__ QOF2,
                          float* __restrict__ OT) {
  int row = blockIdx.x * 2 + (threadIdx.x >> 7);
  int c = threadIdx.x & 127;
  float ali = AL[row];
  float A1 = __expf(ali), A2 = __expf(0.2f * ali);
  float xv = -ali;
  int lo = 0, hi = NT;
  while (lo < hi) {  // upper_bound: #{ar_j <= -al_i} (branch-2 count)
    int mid = (lo + hi) >> 1;
    if (ARS[mid] <= xv) lo = mid + 1; else hi = mid;
  }
  int b = lo - 1;
  float p1 = 0.f, p2 = 0.f, q1 = 0.f, q2 = 0.f;
  if (b >= 0) {
    int ch = b >> 6;
    p1 = P1[b * 128 + c] + (ch ? OFF1[(ch - 1) * 128 + c] : 0.f);
    p2 = P2[b * 128 + c] + (ch ? OFF2[(ch - 1) * 128 + c] : 0.f);
    q1 = Q1L[b] + (ch ? QOF1[ch - 1] : 0.f);
    q2 = Q2L[b] + (ch ? QOF2[ch - 1] : 0.f);
  }
  float T1 = OFF1[127 * 128 + c];
  float QT1 = QOF1[127];
  float num = A1 * (T1 - p1) + A2 * p2;
  float den = A1 * (QT1 - q1) + A2 * q2;
  OT[row * 128 + c] = X[row * 128 + c] - num / den;
}

// mean aggregation over CSR (self-loop included), feat = [x | ot]
__global__ void k_aggr(const float* __restrict__ X, const float* __restrict__ OT,
                       const int* __restrict__ OFFS, const int* __restrict__ ADJ,
                       float* __restrict__ AGGR) {
  int bid = blockIdx.x;
  int node = bid & (NN - 1);
  int g = bid >> 12;
  int c = threadIdx.x;  // 256
  const int* off = OFFS + g * (NN + 1);
  const int* adj = ADJ + g * NE;
  int beg = off[node], end = off[node + 1];
  int base = g * NN * 128;
  float acc = (c < 128) ? X[base + node * 128 + c] : OT[base + node * 128 + (c - 128)];
  for (int e = beg; e < end; ++e) {
    int d = adj[e];
    acc += (c < 128) ? X[base + d * 128 + c] : OT[base + d * 128 + (c - 128)];
  }
  AGGR[(size_t)bid * 256 + c] = acc / (float)(end - beg + 1);
}

// small GEMM: out[row][c] = sum_k act(A[row][k]) * WT[k][c] + bias[c]
template <int KD, bool RELU, bool OBF>
__global__ __launch_bounds__(128) void k_gemm(const float* __restrict__ A,
                                              const float* __restrict__ WT,
                                              const float* __restrict__ bias,
                                              void* __restrict__ out) {
  int c = threadIdx.x;       // 128
  int r0 = blockIdx.x * 16;  // 16 rows per block
  float acc[16];
  float bc = bias[c];
  #pragma unroll
  for (int i = 0; i < 16; ++i) acc[i] = bc;
  for (int k = 0; k < KD; ++k) {
    float wv = WT[k * 128 + c];
    #pragma unroll
    for (int i = 0; i < 16; ++i) {
      float a = A[(r0 + i) * KD + k];
      if (RELU) a = fmaxf(a, 0.f);
      acc[i] += a * wv;
    }
  }
  if (OBF) {
    __hip_bfloat16* o = (__hip_bfloat16*)out;
    #pragma unroll
    for (int i = 0; i < 16; ++i) o[(r0 + i) * 128 + c] = __float2bfloat16(acc[i]);
  } else {
    float* o = (float*)out;
    #pragma unroll
    for (int i = 0; i < 16; ++i) o[(r0 + i) * 128 + c] = acc[i];
  }
}

// ---------------- final: out = sigmoid(F F^T), F bf16 8192x128 ----------------
__device__ inline f32x16 zero16() {
  f32x16 v;
  #pragma unroll
  for (int i = 0; i < 16; ++i) v[i] = 0.f;
  return v;
}

__device__ inline void store_frag(float* __restrict__ out, const f32x16& a,
                                  int grow0, int gcol) {
  #pragma unroll
  for (int r = 0; r < 16; ++r) {
    int rloc = (r & 3) + 8 * (r >> 2);  // C/D: row=(reg&3)+8*(reg>>2)+4*(lane>>5)
    float v = a[r];
    out[(size_t)(grow0 + rloc) * 8192 + gcol] = 1.f / (1.f + __expf(-v));
  }
}

__global__ __launch_bounds__(256) void k_final(const unsigned short* __restrict__ F,
                                               float* __restrict__ out) {
  __shared__ unsigned short AT[128 * 128];
  __shared__ unsigned short BT[128 * 128];
  int cb = blockIdx.x, rb = blockIdx.y;
  int tid = threadIdx.x;
  // stage two 128x128 bf16 tiles, XOR-swizzled rows (bank-conflict fix)
  #pragma unroll
  for (int q = 0; q < 8; ++q) {
    int idx = q * 256 + tid;       // 0..2047
    int r = idx >> 4, ck = idx & 15;
    unsigned off = (unsigned)((r * 256 + ck * 16) ^ ((r & 7) << 4));
    uint4 va = *(const uint4*)(F + (size_t)(rb * 128 + r) * 128 + ck * 8);
    *(uint4*)((char*)AT + off) = va;
    uint4 vb = *(const uint4*)(F + (size_t)(cb * 128 + r) * 128 + ck * 8);
    *(uint4*)((char*)BT + off) = vb;
  }
  __syncthreads();
  int lane = tid & 63, w = tid >> 6;
  int wr = w >> 1, wc = w & 1;
  int l31 = lane & 31, kh = lane >> 5;
  int xorm = (l31 & 7) << 4;
  int rowA0 = wr * 64 + l31, rowA1 = rowA0 + 32;
  int rowB0 = wc * 64 + l31, rowB1 = rowB0 + 32;
  f32x16 a00 = zero16(), a01 = zero16(), a10 = zero16(), a11 = zero16();
  #pragma unroll
  for (int ks = 0; ks < 8; ++ks) {
    int kb = ks * 32 + kh * 16;
    bf16x8 av0 = *(const bf16x8*)((const char*)AT + ((rowA0 * 256 + kb) ^ xorm));
    bf16x8 av1 = *(const bf16x8*)((const char*)AT + ((rowA1 * 256 + kb) ^ xorm));
    bf16x8 bv0 = *(const bf16x8*)((const char*)BT + ((rowB0 * 256 + kb) ^ xorm));
    bf16x8 bv1 = *(const bf16x8*)((const char*)BT + ((rowB1 * 256 + kb) ^ xorm));
    a00 = __builtin_amdgcn_mfma_f32_32x32x16_bf16(av0, bv0, a00, 0, 0, 0);
    a01 = __builtin_amdgcn_mfma_f32_32x32x16_bf16(av0, bv1, a01, 0, 0, 0);
    a10 = __builtin_amdgcn_mfma_f32_32x32x16_bf16(av1, bv0, a10, 0, 0, 0);
    a11 = __builtin_amdgcn_mfma_f32_32x32x16_bf16(av1, bv1, a11, 0, 0, 0);
  }
  int grow = rb * 128 + wr * 64 + 4 * kh;
  int gcol = cb * 128 + wc * 64 + l31;
  store_frag(out, a00, grow, gcol);
  store_frag(out, a01, grow, gcol + 32);
  store_frag(out, a10, grow + 32, gcol);
  store_frag(out, a11, grow + 32, gcol + 32);
}

// ---------------- host ----------------
extern "C" void kernel_launch(void* const* d_in, const int* in_sizes, int n_in,
                              void* d_out, int out_size, void* d_ws, size_t ws_size,
                              hipStream_t stream) {
  (void)in_sizes; (void)n_in; (void)out_size; (void)ws_size;
  const float* x1 = (const float*)d_in[0];
  const float* x2 = (const float*)d_in[1];
  const int* ei1 = (const int*)d_in[2];
  const int* ei2 = (const int*)d_in[3];
  const float* wl_w[2] = {(const float*)d_in[4], (const float*)d_in[10]};
  const float* wl_b[2] = {(const float*)d_in[5], (const float*)d_in[11]};
  const float* wr_w[2] = {(const float*)d_in[6], (const float*)d_in[12]};
  const float* wr_b[2] = {(const float*)d_in[7], (const float*)d_in[13]};
  const float* alv[2] = {(const float*)d_in[8], (const float*)d_in[14]};
  const float* arv[2] = {(const float*)d_in[9], (const float*)d_in[15]};
  const float* ww_w[2] = {(const float*)d_in[16], (const float*)d_in[18]};
  const float* ww_b[2] = {(const float*)d_in[17], (const float*)d_in[19]};
  const float* lin_w = (const float*)d_in[20];
  const float* lin_b = (const float*)d_in[21];

  char* wp = (char*)d_ws;
  auto alloc = [&](size_t b) -> char* {
    char* p = wp;
    wp += (b + 255) & ~(size_t)255;
    return p;
  };
  float* XA = (float*)alloc((size_t)NT * CD * 4);
  float* XB = (float*)alloc((size_t)NT * CD * 4);
  float* OT = (float*)alloc((size_t)NT * CD * 4);
  float* P1 = (float*)alloc((size_t)NT * CD * 4);   // also aliased as AGGR (P1..P2, 8MB)
  float* P2 = (float*)alloc((size_t)NT * CD * 4);
  float* AGGR = P1;  // P1,P2 dead once k_combine ran; k_aggr reuses the 8MB
  float* CT1 = (float*)alloc(128 * 128 * 4);
  float* CT2 = (float*)alloc(128 * 128 * 4);
  float* OFF1 = (float*)alloc(128 * 128 * 4);
  float* OFF2 = (float*)alloc(128 * 128 * 4);
  float* AL = (float*)alloc(NT * 4);
  float* AR_ = (float*)alloc(NT * 4);
  float* ARS = (float*)alloc(NT * 4);
  float* W1S = (float*)alloc(NT * 4);
  float* W2S = (float*)alloc(NT * 4);
  float* Q1L = (float*)alloc(NT * 4);
  float* Q2L = (float*)alloc(NT * 4);
  float* QCT1 = (float*)alloc(128 * 4);
  float* QCT2 = (float*)alloc(128 * 4);
  float* QOF1 = (float*)alloc(128 * 4);
  float* QOF2 = (float*)alloc(128 * 4);
  float* VP = (float*)alloc(258 * 4);
  float* WT1 = (float*)alloc(256 * 128 * 4);
  float* WT2 = (float*)alloc(256 * 128 * 4);
  float* WTL = (float*)alloc(128 * 128 * 4);
  int* RANK = (int*)alloc(NT * 4);
  int* PERM = (int*)alloc(NT * 4);
  int* DEG = (int*)alloc(2 * NN * 4);
  int* OFFS = (int*)alloc(2 * (NN + 1) * 4);
  int* CURS = (int*)alloc(2 * NN * 4);
  int* ADJ = (int*)alloc(2 * NE * 4);
  unsigned short* FBF = (unsigned short*)OT;  // OT dead after last k_aggr

  // X = concat(x1, x2)
  hipMemcpyAsync(XA, x1, (size_t)NN * CD * 4, hipMemcpyDeviceToDevice, stream);
  hipMemcpyAsync(XA + (size_t)NN * CD, x2, (size_t)NN * CD * 4, hipMemcpyDeviceToDevice, stream);
  hipMemsetAsync(DEG, 0, 2 * NN * 4, stream);
  k_transW<<<320, 256, 0, stream>>>(ww_w[0], ww_w[1], lin_w, WT1, WT2, WTL);
  k_deg<<<512, 256, 0, stream>>>(ei1, ei2, DEG);
  k_scanoff<<<2, 256, 0, stream>>>(DEG, OFFS, CURS);
  k_fill<<<512, 256, 0, stream>>>(ei1, ei2, CURS, ADJ);

  float* X = XA;
  float* XN = XB;
  for (int L = 0; L < 2; ++L) {
    k_params<<<1, 128, 0, stream>>>(wl_w[L], wl_b[L], wr_w[L], wr_b[L], alv[L], arv[L], VP);
    k_alar<<<2048, 256, 0, stream>>>(X, VP, AL, AR_);
    hipMemsetAsync(RANK, 0, NT * 4, stream);
    k_rank<<<dim3(32, 8), 256, 0, stream>>>(AR_, RANK);
    k_perm<<<32, 256, 0, stream>>>(RANK, AR_, PERM, ARS, W1S, W2S);
    k_scanA<<<128, 320, 0, stream>>>(X, PERM, W1S, W2S, P1, P2, CT1, CT2, Q1L, Q2L, QCT1, QCT2);
    k_scanB<<<1, 320, 0, stream>>>(CT1, CT2, QCT1, QCT2, OFF1, OFF2, QOF1, QOF2);
    k_combine<<<4096, 256, 0, stream>>>(X, AL, ARS, P1, P2, OFF1, OFF2, Q1L, Q2L, QOF1, QOF2, OT);
    k_aggr<<<8192, 256, 0, stream>>>(X, OT, OFFS, ADJ, AGGR);
    k_gemm<256, true, false><<<512, 128, 0, stream>>>(AGGR, L ? WT2 : WT1, ww_b[L], XN);
    float* t = X; X = XN; XN = t;
  }
  // feats (bf16) = X @ lin^T + lin_b
  k_gemm<128, false, true><<<512, 128, 0, stream>>>(X, WTL, lin_b, FBF);
  // out = sigmoid(F F^T)
  k_final<<<dim3(64, 64), 256, 0, stream>>>(FBF, (float*)d_out);
}

// Round 3
// 322.391 us; speedup vs baseline: 1.4797x; 1.4797x over previous
//
#include <hip/hip_runtime.h>
#include <hip/hip_bf16.h>

#define NT 8192   // total nodes (2 graphs)
#define NN 4096   // nodes per graph
#define CD 128    // channels
#define NE 65536  // edges per graph

typedef __attribute__((ext_vector_type(8))) short bf16x8;
typedef __attribute__((ext_vector_type(16))) float f32x16;
typedef __attribute__((ext_vector_type(4))) float f32x4;

// ---------------- prep: weight transposes + attention params + DEG zero ----------------
// blocks 0..319: transpose W1/W2/WL; 320/321: params layer0/1; 322..353: zero DEG
__global__ __launch_bounds__(256) void k_prep(
    const float* __restrict__ W1, const float* __restrict__ W2, const float* __restrict__ WL,
    float* __restrict__ WT1, float* __restrict__ WT2, float* __restrict__ WTL,
    const float* __restrict__ wlw0, const float* __restrict__ wlb0,
    const float* __restrict__ wrw0, const float* __restrict__ wrb0,
    const float* __restrict__ al0, const float* __restrict__ ar0,
    const float* __restrict__ wlw1, const float* __restrict__ wlb1,
    const float* __restrict__ wrw1, const float* __restrict__ wrb1,
    const float* __restrict__ al1, const float* __restrict__ ar1,
    float* __restrict__ VP, int* __restrict__ DEG) {
  int b = blockIdx.x, tid = threadIdx.x;
  if (b < 320) {
    int idx = b * 256 + tid;
    if (idx < 32768) { int c = idx >> 8, k = idx & 255; WT1[k * 128 + c] = W1[idx]; }
    else if (idx < 65536) { int j = idx - 32768; int c = j >> 8, k = j & 255; WT2[k * 128 + c] = W2[j]; }
    else { int j = idx - 65536; int c = j >> 7, k = j & 127; WTL[k * 128 + c] = WL[j]; }
  } else if (b < 322) {
    int L = b - 320;
    const float* wlw = L ? wlw1 : wlw0;
    const float* wlb = L ? wlb1 : wlb0;
    const float* wrw = L ? wrw1 : wrw0;
    const float* wrb = L ? wrb1 : wrb0;
    const float* alv = L ? al1 : al0;
    const float* arv = L ? ar1 : ar0;
    float* vp = VP + L * 258;
    if (tid < 128) {
      int c = tid;
      float sl = 0.f, sr = 0.f;
      for (int h = 0; h < 128; ++h) {
        sl += wlw[h * 128 + c] * alv[h];
        sr += wrw[h * 128 + c] * arv[h];
      }
      vp[c] = sl;
      vp[128 + c] = sr;
      if (c < 2) {
        const float* bb = c ? wrb : wlb;
        const float* aa = c ? arv : alv;
        float s = 0.f;
        for (int h = 0; h < 128; ++h) s += bb[h] * aa[h];
        vp[256 + c] = s;
      }
    }
  } else {
    int idx = (b - 322) * 256 + tid;  // 8192
    DEG[idx] = 0;
  }
}

// ---------------- CSR build (once; edges shared by both layers) ----------------
__global__ void k_deg(const int* __restrict__ EI1, const int* __restrict__ EI2,
                      int* __restrict__ DEG) {
  int idx = blockIdx.x * 256 + threadIdx.x;   // 131072
  int g = idx >> 16, e = idx & 65535;
  const int* src = g ? EI2 : EI1;
  atomicAdd(&DEG[g * NN + src[e]], 1);
}

__global__ void k_scanoff(const int* __restrict__ DEG, int* __restrict__ OFFS,
                          int* __restrict__ CURS) {
  int g = blockIdx.x, tid = threadIdx.x;
  __shared__ int part[256];
  int loc[16];
  int s = 0;
  #pragma unroll
  for (int i = 0; i < 16; ++i) { loc[i] = s; s += DEG[g * NN + tid * 16 + i]; }
  part[tid] = s;
  __syncthreads();
  for (int d = 1; d < 256; d <<= 1) {
    int v = part[tid];
    int o = (tid >= d) ? part[tid - d] : 0;
    __syncthreads();
    part[tid] = v + o;
    __syncthreads();
  }
  int excl = tid ? part[tid - 1] : 0;
  #pragma unroll
  for (int i = 0; i < 16; ++i) {
    int o = excl + loc[i];
    OFFS[g * (NN + 1) + tid * 16 + i] = o;
    CURS[g * NN + tid * 16 + i] = o;
  }
  if (tid == 255) OFFS[g * (NN + 1) + NN] = part[255];
}

__global__ void k_fill(const int* __restrict__ EI1, const int* __restrict__ EI2,
                       int* __restrict__ CURS, int* __restrict__ ADJ) {
  int idx = blockIdx.x * 256 + threadIdx.x;
  int g = idx >> 16, e = idx & 65535;
  const int* ei = g ? EI2 : EI1;
  int s = ei[e], d = ei[NE + e];
  int pos = atomicAdd(&CURS[g * NN + s], 1);
  ADJ[g * NE + pos] = d;
}

// a_l[i] = X[i].vl + cl ; a_r[i] = X[i].vr + cr  (one wave per row); blocks 0..31 zero RANK
__global__ void k_alar(const float* __restrict__ X, const float* __restrict__ VP,
                       float* __restrict__ AL, float* __restrict__ AR,
                       int* __restrict__ RANK) {
  if (blockIdx.x < 32) RANK[blockIdx.x * 256 + threadIdx.x] = 0;
  int lane = threadIdx.x & 63;
  int row = blockIdx.x * 4 + (threadIdx.x >> 6);
  float x0 = X[row * 128 + lane], x1 = X[row * 128 + 64 + lane];
  float sl = x0 * VP[lane] + x1 * VP[64 + lane];
  float sr = x0 * VP[128 + lane] + x1 * VP[192 + lane];
  #pragma unroll
  for (int m = 1; m < 64; m <<= 1) {
    sl += __shfl_xor(sl, m, 64);
    sr += __shfl_xor(sr, m, 64);
  }
  if (lane == 0) { AL[row] = sl + VP[256]; AR[row] = sr + VP[257]; }
}

// rank of each j under total order (a_r, j)  -> O(N^2) chunked count, int atomics
__global__ void k_rank(const float* __restrict__ AR, int* __restrict__ RANK) {
  __shared__ float tile[1024];
  int j = blockIdx.x * 256 + threadIdx.x;
  int base = blockIdx.y * 1024;
  for (int t = threadIdx.x; t < 1024; t += 256) tile[t] = AR[base + t];
  __syncthreads();
  float aj = AR[j];
  int cnt = 0;
  #pragma unroll 8
  for (int u = 0; u < 1024; ++u) {
    float a2 = tile[u];
    cnt += (a2 < aj || (a2 == aj && (base + u) < j)) ? 1 : 0;
  }
  atomicAdd(&RANK[j], cnt);
}

// scatter permutation + sorted a_r
__global__ void k_perm(const int* __restrict__ RANK, const float* __restrict__ AR,
                       int* __restrict__ PERM, float* __restrict__ ARS) {
  int j = blockIdx.x * 256 + threadIdx.x;
  int r = RANK[j];
  PERM[r] = j;
  ARS[r] = AR[j];
}

// hierarchical prefix sums along sorted axis: chunks of 64, 128 chunks
__global__ __launch_bounds__(320) void k_scanA(
    const float* __restrict__ X, const int* __restrict__ PERM,
    const float* __restrict__ ARS,
    float* __restrict__ P1, float* __restrict__ P2,
    float* __restrict__ CT1, float* __restrict__ CT2,
    float* __restrict__ Q1L, float* __restrict__ Q2L,
    float* __restrict__ QCT1, float* __restrict__ QCT2) {
  __shared__ int pc[64];
  __shared__ float w1[64], w2[64];
  int chunk = blockIdx.x, tid = threadIdx.x;
  if (tid < 64) {
    int r = chunk * 64 + tid;
    pc[tid] = PERM[r];
    float a = ARS[r];
    w1[tid] = __expf(a);
    w2[tid] = __expf(0.2f * a);
  }
  __syncthreads();
  if (tid < 128) {
    int c = tid;
    float acc = 0.f;
    #pragma unroll 4
    for (int t = 0; t < 64; ++t) {
      acc += w1[t] * X[pc[t] * 128 + c];
      P1[(chunk * 64 + t) * 128 + c] = acc;
    }
    CT1[chunk * 128 + c] = acc;
  } else if (tid < 256) {
    int c = tid - 128;
    float acc = 0.f;
    #pragma unroll 4
    for (int t = 0; t < 64; ++t) {
      acc += w2[t] * X[pc[t] * 128 + c];
      P2[(chunk * 64 + t) * 128 + c] = acc;
    }
    CT2[chunk * 128 + c] = acc;
  } else if (tid == 256) {
    float acc = 0.f;
    for (int t = 0; t < 64; ++t) { acc += w1[t]; Q1L[chunk * 64 + t] = acc; }
    QCT1[chunk] = acc;
  } else if (tid == 257) {
    float acc = 0.f;
    for (int t = 0; t < 64; ++t) { acc += w2[t]; Q2L[chunk * 64 + t] = acc; }
    QCT2[chunk] = acc;
  }
}

__global__ __launch_bounds__(320) void k_scanB(
    const float* __restrict__ CT1, const float* __restrict__ CT2,
    const float* __restrict__ QCT1, const float* __restrict__ QCT2,
    float* __restrict__ OFF1, float* __restrict__ OFF2,
    float* __restrict__ QOF1, float* __restrict__ QOF2) {
  int tid = threadIdx.x;
  if (tid < 128) {
    float acc = 0.f;
    #pragma unroll 8
    for (int ch = 0; ch < 128; ++ch) { acc += CT1[ch * 128 + tid]; OFF1[ch * 128 + tid] = acc; }
  } else if (tid < 256) {
    int c = tid - 128;
    float acc = 0.f;
    #pragma unroll 8
    for (int ch = 0; ch < 128; ++ch) { acc += CT2[ch * 128 + c]; OFF2[ch * 128 + c] = acc; }
  } else if (tid == 256) {
    float acc = 0.f;
    for (int ch = 0; ch < 128; ++ch) { acc += QCT1[ch]; QOF1[ch] = acc; }
  } else if (tid == 257) {
    float acc = 0.f;
    for (int ch = 0; ch < 128; ++ch) { acc += QCT2[ch]; QOF2[ch] = acc; }
  }
}

// ot[i] = x[i] - (A1*suffix1 + A2*prefix2)/(A1*qsuf1 + A2*qpre2)
__global__ void k_combine(const float* __restrict__ X, const float* __restrict__ AL,
                          const float* __restrict__ ARS,
                          const float* __restrict__ P1, const float* __restrict__ P2,
                          const float* __restrict__ OFF1, const float* __restrict__ OFF2,
                          const float* __restrict__ Q1L, const float* __restrict__ Q2L,
                          const float* __restrict__ QOF1, const float* __restrict__ QOF2,
                          float* __restrict__ OT) {
  int row = blockIdx.x * 2 + (threadIdx.x >> 7);
  int c = threadIdx.x & 127;
  float ali = AL[row];
  float A1 = __expf(ali), A2 = __expf(0.2f * ali);
  float xv = -ali;
  int lo = 0, hi = NT;
  while (lo < hi) {  // upper_bound: #{ar_j <= -al_i} (branch-2 count)
    int mid = (lo + hi) >> 1;
    if (ARS[mid] <= xv) lo = mid + 1; else hi = mid;
  }
  int b = lo - 1;
  float p1 = 0.f, p2 = 0.f, q1 = 0.f, q2 = 0.f;
  if (b >= 0) {
    int ch = b >> 6;
    p1 = P1[b * 128 + c] + (ch ? OFF1[(ch - 1) * 128 + c] : 0.f);
    p2 = P2[b * 128 + c] + (ch ? OFF2[(ch - 1) * 128 + c] : 0.f);
    q1 = Q1L[b] + (ch ? QOF1[ch - 1] : 0.f);
    q2 = Q2L[b] + (ch ? QOF2[ch - 1] : 0.f);
  }
  float T1 = OFF1[127 * 128 + c];
  float QT1 = QOF1[127];
  float num = A1 * (T1 - p1) + A2 * p2;
  float den = A1 * (QT1 - q1) + A2 * q2;
  OT[row * 128 + c] = X[row * 128 + c] - num / den;
}

// mean aggregation over CSR (self-loop included), feat = [x | ot]; wave-per-node, f32x4 lanes
__global__ __launch_bounds__(256) void k_aggr(const float* __restrict__ X,
                                              const float* __restrict__ OT,
                                              const int* __restrict__ OFFS,
                                              const int* __restrict__ ADJ,
                                              float* __restrict__ AGGR) {
  int node = blockIdx.x * 4 + (threadIdx.x >> 6);
  int lane = threadIdx.x & 63;
  int g = node >> 12, n = node & (NN - 1);
  const int* off = OFFS + g * (NN + 1);
  const int* adj = ADJ + g * NE;
  int beg = off[n], end = off[n + 1];
  const f32x4* src = (const f32x4*)((lane < 32 ? X : OT) + (size_t)g * NN * CD);
  int c4 = lane & 31;
  f32x4 acc = src[n * 32 + c4];
  for (int e = beg; e < end; ++e) {
    int d = adj[e];
    acc += src[d * 32 + c4];
  }
  f32x4 r = acc / (float)(end - beg + 1);
  ((f32x4*)AGGR)[(size_t)node * 64 + (lane < 32 ? c4 : 32 + c4)] = r;
}

// small GEMM: out[row][c] = sum_k act(A[row][k]) * WT[k][c] + bias[c]; 8 rows/block, LDS-staged A
template <int KD, bool RELU, bool OBF>
__global__ __launch_bounds__(128) void k_gemm(const float* __restrict__ A,
                                              const float* __restrict__ WT,
                                              const float* __restrict__ bias,
                                              void* __restrict__ out) {
  __shared__ float sA[8 * KD];
  int c = threadIdx.x;      // 128
  int r0 = blockIdx.x * 8;  // 8 rows per block
  for (int i = c; i < 8 * KD; i += 128) {
    float a = A[(size_t)r0 * KD + i];
    if (RELU) a = fmaxf(a, 0.f);
    sA[i] = a;
  }
  __syncthreads();
  float acc[8];
  float bc = bias[c];
  #pragma unroll
  for (int i = 0; i < 8; ++i) acc[i] = bc;
  for (int k = 0; k < KD; ++k) {
    float wv = WT[k * 128 + c];
    #pragma unroll
    for (int i = 0; i < 8; ++i) acc[i] += sA[i * KD + k] * wv;
  }
  if (OBF) {
    __hip_bfloat16* o = (__hip_bfloat16*)out;
    #pragma unroll
    for (int i = 0; i < 8; ++i) o[(r0 + i) * 128 + c] = __float2bfloat16(acc[i]);
  } else {
    float* o = (float*)out;
    #pragma unroll
    for (int i = 0; i < 8; ++i) o[(r0 + i) * 128 + c] = acc[i];
  }
}

// ---------------- final: out = sigmoid(F F^T), F bf16 8192x128 ----------------
__device__ inline f32x16 zero16() {
  f32x16 v;
  #pragma unroll
  for (int i = 0; i < 16; ++i) v[i] = 0.f;
  return v;
}

__device__ inline void store_frag(float* __restrict__ out, const f32x16& a,
                                  int grow0, int gcol) {
  #pragma unroll
  for (int r = 0; r < 16; ++r) {
    int rloc = (r & 3) + 8 * (r >> 2);  // C/D: row=(reg&3)+8*(reg>>2)+4*(lane>>5)
    float v = a[r];
    out[(size_t)(grow0 + rloc) * 8192 + gcol] =
        __builtin_amdgcn_rcpf(1.f + __expf(-v));
  }
}

__global__ __launch_bounds__(256) void k_final(const unsigned short* __restrict__ F,
                                               float* __restrict__ out) {
  __shared__ unsigned short AT[128 * 128];
  __shared__ unsigned short BT[128 * 128];
  int cb = blockIdx.x, rb = blockIdx.y;
  int tid = threadIdx.x;
  // stage two 128x128 bf16 tiles, XOR-swizzled rows (bank-conflict fix)
  #pragma unroll
  for (int q = 0; q < 8; ++q) {
    int idx = q * 256 + tid;       // 0..2047
    int r = idx >> 4, ck = idx & 15;
    unsigned off = (unsigned)((r * 256 + ck * 16) ^ ((r & 7) << 4));
    uint4 va = *(const uint4*)(F + (size_t)(rb * 128 + r) * 128 + ck * 8);
    *(uint4*)((char*)AT + off) = va;
    uint4 vb = *(const uint4*)(F + (size_t)(cb * 128 + r) * 128 + ck * 8);
    *(uint4*)((char*)BT + off) = vb;
  }
  __syncthreads();
  int lane = tid & 63, w = tid >> 6;
  int wr = w >> 1, wc = w & 1;
  int l31 = lane & 31, kh = lane >> 5;
  int xorm = (l31 & 7) << 4;
  int rowA0 = wr * 64 + l31, rowA1 = rowA0 + 32;
  int rowB0 = wc * 64 + l31, rowB1 = rowB0 + 32;
  f32x16 a00 = zero16(), a01 = zero16(), a10 = zero16(), a11 = zero16();
  #pragma unroll
  for (int ks = 0; ks < 8; ++ks) {
    int kb = ks * 32 + kh * 16;
    bf16x8 av0 = *(const bf16x8*)((const char*)AT + ((rowA0 * 256 + kb) ^ xorm));
    bf16x8 av1 = *(const bf16x8*)((const char*)AT + ((rowA1 * 256 + kb) ^ xorm));
    bf16x8 bv0 = *(const bf16x8*)((const char*)BT + ((rowB0 * 256 + kb) ^ xorm));
    bf16x8 bv1 = *(const bf16x8*)((const char*)BT + ((rowB1 * 256 + kb) ^ xorm));
    a00 = __builtin_amdgcn_mfma_f32_32x32x16_bf16(av0, bv0, a00, 0, 0, 0);
    a01 = __builtin_amdgcn_mfma_f32_32x32x16_bf16(av0, bv1, a01, 0, 0, 0);
    a10 = __builtin_amdgcn_mfma_f32_32x32x16_bf16(av1, bv0, a10, 0, 0, 0);
    a11 = __builtin_amdgcn_mfma_f32_32x32x16_bf16(av1, bv1, a11, 0, 0, 0);
  }
  int grow = rb * 128 + wr * 64 + 4 * kh;
  int gcol = cb * 128 + wc * 64 + l31;
  store_frag(out, a00, grow, gcol);
  store_frag(out, a01, grow, gcol + 32);
  store_frag(out, a10, grow + 32, gcol);
  store_frag(out, a11, grow + 32, gcol + 32);
}

// ---------------- host ----------------
extern "C" void kernel_launch(void* const* d_in, const int* in_sizes, int n_in,
                              void* d_out, int out_size, void* d_ws, size_t ws_size,
                              hipStream_t stream) {
  (void)in_sizes; (void)n_in; (void)out_size; (void)ws_size;
  const float* x1 = (const float*)d_in[0];
  const float* x2 = (const float*)d_in[1];
  const int* ei1 = (const int*)d_in[2];
  const int* ei2 = (const int*)d_in[3];
  const float* wl_w[2] = {(const float*)d_in[4], (const float*)d_in[10]};
  const float* wl_b[2] = {(const float*)d_in[5], (const float*)d_in[11]};
  const float* wr_w[2] = {(const float*)d_in[6], (const float*)d_in[12]};
  const float* wr_b[2] = {(const float*)d_in[7], (const float*)d_in[13]};
  const float* alv[2] = {(const float*)d_in[8], (const float*)d_in[14]};
  const float* arv[2] = {(const float*)d_in[9], (const float*)d_in[15]};
  const float* ww_w[2] = {(const float*)d_in[16], (const float*)d_in[18]};
  const float* ww_b[2] = {(const float*)d_in[17], (const float*)d_in[19]};
  const float* lin_w = (const float*)d_in[20];
  const float* lin_b = (const float*)d_in[21];

  char* wp = (char*)d_ws;
  auto alloc = [&](size_t b) -> char* {
    char* p = wp;
    wp += (b + 255) & ~(size_t)255;
    return p;
  };
  float* XA = (float*)alloc((size_t)NT * CD * 4);
  float* XB = (float*)alloc((size_t)NT * CD * 4);
  float* OT = (float*)alloc((size_t)NT * CD * 4);
  float* P1 = (float*)alloc((size_t)NT * CD * 4);
  float* P2 = (float*)alloc((size_t)NT * CD * 4);
  float* AGGR = P1;  // P1,P2 dead once k_combine ran; k_aggr reuses the 8MB
  float* CT1 = (float*)alloc(128 * 128 * 4);
  float* CT2 = (float*)alloc(128 * 128 * 4);
  float* OFF1 = (float*)alloc(128 * 128 * 4);
  float* OFF2 = (float*)alloc(128 * 128 * 4);
  float* AL = (float*)alloc(NT * 4);
  float* AR_ = (float*)alloc(NT * 4);
  float* ARS = (float*)alloc(NT * 4);
  float* Q1L = (float*)alloc(NT * 4);
  float* Q2L = (float*)alloc(NT * 4);
  float* QCT1 = (float*)alloc(128 * 4);
  float* QCT2 = (float*)alloc(128 * 4);
  float* QOF1 = (float*)alloc(128 * 4);
  float* QOF2 = (float*)alloc(128 * 4);
  float* VP = (float*)alloc(2 * 258 * 4);
  float* WT1 = (float*)alloc(256 * 128 * 4);
  float* WT2 = (float*)alloc(256 * 128 * 4);
  float* WTL = (float*)alloc(128 * 128 * 4);
  int* RANK = (int*)alloc(NT * 4);
  int* PERM = (int*)alloc(NT * 4);
  int* DEG = (int*)alloc(2 * NN * 4);
  int* OFFS = (int*)alloc(2 * (NN + 1) * 4);
  int* CURS = (int*)alloc(2 * NN * 4);
  int* ADJ = (int*)alloc(2 * NE * 4);
  unsigned short* FBF = (unsigned short*)OT;  // OT dead after last k_aggr

  // X = concat(x1, x2)
  hipMemcpyAsync(XA, x1, (size_t)NN * CD * 4, hipMemcpyDeviceToDevice, stream);
  hipMemcpyAsync(XA + (size_t)NN * CD, x2, (size_t)NN * CD * 4, hipMemcpyDeviceToDevice, stream);
  k_prep<<<354, 256, 0, stream>>>(ww_w[0], ww_w[1], lin_w, WT1, WT2, WTL,
                                  wl_w[0], wl_b[0], wr_w[0], wr_b[0], alv[0], arv[0],
                                  wl_w[1], wl_b[1], wr_w[1], wr_b[1], alv[1], arv[1],
                                  VP, DEG);
  k_deg<<<512, 256, 0, stream>>>(ei1, ei2, DEG);
  k_scanoff<<<2, 256, 0, stream>>>(DEG, OFFS, CURS);
  k_fill<<<512, 256, 0, stream>>>(ei1, ei2, CURS, ADJ);

  float* X = XA;
  float* XN = XB;
  for (int L = 0; L < 2; ++L) {
    k_alar<<<2048, 256, 0, stream>>>(X, VP + L * 258, AL, AR_, RANK);
    k_rank<<<dim3(32, 8), 256, 0, stream>>>(AR_, RANK);
    k_perm<<<32, 256, 0, stream>>>(RANK, AR_, PERM, ARS);
    k_scanA<<<128, 320, 0, stream>>>(X, PERM, ARS, P1, P2, CT1, CT2, Q1L, Q2L, QCT1, QCT2);
    k_scanB<<<1, 320, 0, stream>>>(CT1, CT2, QCT1, QCT2, OFF1, OFF2, QOF1, QOF2);
    k_combine<<<4096, 256, 0, stream>>>(X, AL, ARS, P1, P2, OFF1, OFF2, Q1L, Q2L, QOF1, QOF2, OT);
    k_aggr<<<2048, 256, 0, stream>>>(X, OT, OFFS, ADJ, AGGR);
    k_gemm<256, true, false><<<1024, 128, 0, stream>>>(AGGR, L ? WT2 : WT1, ww_b[L], XN);
    float* t = X; X = XN; XN = t;
  }
  // feats (bf16) = X @ lin^T + lin_b
  k_gemm<128, false, true><<<1024, 128, 0, stream>>>(X, WTL, lin_b, FBF);
  // out = sigmoid(F F^T)
  k_final<<<dim3(64, 64), 256, 0, stream>>>(FBF, (float*)d_out);
}